// Round 16
// baseline (237.935 us; speedup 1.0000x reference)
//
#include <hip/hip_runtime.h>
#include <math.h>

#define NPIX 1024
#define NBOX 9216
#define ECAP 6144        // edge capacity (measured E ~ 500)

typedef unsigned long long u64;

// ---------------- workspace layout (bytes), R5/R10 layout ----------------
#define O_PART     0u           // 16 x 1 MiB (16 x 262144 f32)
#define O_H        0u           // aliases partial slot 0
#define O_BOXES    1048576u     // 9216*4 f32
#define O_CONF     1196032u     // 9216 f32
#define O_KEYS     1232896u     // 9216 u64
#define O_ORDER    1306624u     // 9216 i32
#define O_SBOX     1343488u     // 9216*4 f32
#define O_SAREA    1490944u     // 9216 f32
#define O_EDGES    1527808u     // 6144 u32
#define O_RPART    1553920u     // 36*9216 i32 -> ends 2881024
#define O_VCNT     16777216u    // 1 i32 (Ecnt at +4)
#define O_ECNT     16777220u

// R15 post-mortem: Jacobi resolve WIN (226 -> 204us; serial tid0 chain was
// ~30us). R16: the last pattern-preserving fusion - finalize into resolve
// (R6-validated; saves a ~11us dispatch for ~3us of single-block writes) +
// nms_edges grid 2048 -> 512 (V~500; kill ~1500 launch-and-exit blocks).
// conv1 frozen at R5 form (5 neighborhood probes all regressed).

// ============ conv1: 3x3 SAME, 1280->256, fp32 (R5 form) ============
__global__ __launch_bounds__(256, 4) void conv1_kernel(const float* __restrict__ feat,
                                                       const float* __restrict__ w1,
                                                       float* __restrict__ partial,
                                                       int* __restrict__ VE) {
    const int kc  = blockIdx.x;          // 0..15
    const int cog = blockIdx.y;          // 0..63
    const int tid = threadIdx.x;
    const int x0 = (tid & 7) * 4;        // strip start col
    const int y  = tid >> 3;             // row 0..31
    const int ci0 = kc * 80;
    const int co0 = cog * 4;

    if (kc == 0 && cog == 0 && tid < 2) VE[tid] = 0;   // Vcnt/Ecnt zero (pre-conv2)

    __shared__ float sf[8 * 34 * 32];    // 34.8 KB (only LDS use)

    for (int e = tid; e < 8 * 2 * 32; e += 256) {
        int ci_l = e >> 6, r = (e >> 5) & 1, c = e & 31;
        sf[(ci_l * 34 + r * 33) * 32 + c] = 0.f;
    }

    float acc[4][4];
#pragma unroll
    for (int a = 0; a < 4; ++a)
#pragma unroll
        for (int b = 0; b < 4; ++b) acc[a][b] = 0.f;

    // block-uniform weight base; weight reads are s_load (SMEM pipe),
    // loaded just-before-use (R5 schedule - measured best; R8/R14 regressed).
    const float* wbase = w1 + (size_t)co0 * 11520 + (size_t)ci0 * 9;

    for (int chunk = 0; chunk < 10; ++chunk) {
        const int cbase = ci0 + chunk * 8;
        __syncthreads();
        {
            const float4* fg = (const float4*)(feat + (size_t)cbase * NPIX);
#pragma unroll
            for (int k = 0; k < 8; ++k) {
                int e = tid + k * 256;           // 0..2047
                int ci_l = e >> 8, rem = e & 255;
                int row = rem >> 3, f4c = rem & 7;
                float4 v = fg[ci_l * 256 + rem];
                *(float4*)&sf[(ci_l * 34 + row + 1) * 32 + f4c * 4] = v;
            }
        }
        __syncthreads();

#pragma unroll
        for (int cil = 0; cil < 8; ++cil) {
            float f[3][6];
            const float* base = &sf[(cil * 34 + y) * 32];
#pragma unroll
            for (int dy = 0; dy < 3; ++dy) {
                const float* rp = base + dy * 32;
                float4 mid = *(const float4*)(rp + x0);
                // halo via DPP (VALU pipe). 16-lane row boundary contamination
                // only reaches lanes whose halo is masked (x0==0 / x0==28).
                float lft = __int_as_float(__builtin_amdgcn_update_dpp(
                    0, __float_as_int(mid.w), 0x111 /*row_shr:1*/, 0xF, 0xF, true));
                float rgt = __int_as_float(__builtin_amdgcn_update_dpp(
                    0, __float_as_int(mid.x), 0x101 /*row_shl:1*/, 0xF, 0xF, true));
                f[dy][0] = (x0 == 0) ? 0.f : lft;
                f[dy][1] = mid.x; f[dy][2] = mid.y; f[dy][3] = mid.z; f[dy][4] = mid.w;
                f[dy][5] = (x0 == 28) ? 0.f : rgt;
            }
#pragma unroll
            for (int co = 0; co < 4; ++co) {
                const float* wrow = wbase + (size_t)co * 11520 +
                                    (size_t)(chunk * 8 + cil) * 9;
                float wv[9];
#pragma unroll
                for (int t = 0; t < 9; ++t) wv[t] = wrow[t];
#pragma unroll
                for (int dy = 0; dy < 3; ++dy)
#pragma unroll
                    for (int dx = 0; dx < 3; ++dx) {
                        float wgt = wv[dy * 3 + dx];
#pragma unroll
                        for (int px = 0; px < 4; ++px)
                            acc[co][px] = fmaf(f[dy][px + dx], wgt, acc[co][px]);
                    }
            }
        }
    }

    const int pix = y * 32 + x0;
#pragma unroll
    for (int co = 0; co < 4; ++co) {
        float4 v = {acc[co][0], acc[co][1], acc[co][2], acc[co][3]};
        *(float4*)&partial[((size_t)kc * 256 + co0 + co) * NPIX + pix] = v;
    }
}

// ============ reduce 16 partials + bias + leaky relu (in place: h = slot 0) ============
__global__ __launch_bounds__(256) void conv1_reduce(float* part_h,
                                                    const float* __restrict__ b1) {
    int i = blockIdx.x * 256 + threadIdx.x;
    float s = b1[i >> 10];
#pragma unroll
    for (int kc = 0; kc < 16; ++kc) s += part_h[(size_t)kc * 262144 + i];
    part_h[i] = s > 0.f ? s : 0.01f * s;   // per-thread RAW only
}

// ============ conv2 (1x1) + sigmoid + box decode + sort keys ============
__global__ __launch_bounds__(256) void conv2_decode(const float* __restrict__ h,
                                                    const float* __restrict__ w2,
                                                    const float* __restrict__ b2,
                                                    const float* __restrict__ anchors,
                                                    float* __restrict__ boxes,
                                                    float* __restrict__ conf_arr,
                                                    u64* __restrict__ keys,
                                                    int* __restrict__ Vcnt) {
    int gid = blockIdx.x * 256 + threadIdx.x;   // 0..73727
    int box = gid >> 3, q = gid & 7;            // 8 lanes per box
    int a = box >> 10, p = box & 1023;
    const float* hq  = h + (size_t)(q * 32) * NPIX + p;
    const float* wq  = w2 + (size_t)(a * 6) * 256 + q * 32;
    float s0 = 0.f, s2 = 0.f, s3 = 0.f, s4 = 0.f, s5 = 0.f;
#pragma unroll 4
    for (int ci = 0; ci < 32; ++ci) {
        float hv = hq[(size_t)ci * NPIX];
        s0 = fmaf(hv, wq[0 * 256 + ci], s0);
        s2 = fmaf(hv, wq[2 * 256 + ci], s2);
        s3 = fmaf(hv, wq[3 * 256 + ci], s3);
        s4 = fmaf(hv, wq[4 * 256 + ci], s4);
        s5 = fmaf(hv, wq[5 * 256 + ci], s5);
    }
    s0 += __shfl_xor(s0, 1); s0 += __shfl_xor(s0, 2); s0 += __shfl_xor(s0, 4);
    s2 += __shfl_xor(s2, 1); s2 += __shfl_xor(s2, 2); s2 += __shfl_xor(s2, 4);
    s3 += __shfl_xor(s3, 1); s3 += __shfl_xor(s3, 2); s3 += __shfl_xor(s3, 4);
    s4 += __shfl_xor(s4, 1); s4 += __shfl_xor(s4, 2); s4 += __shfl_xor(s4, 4);
    s5 += __shfl_xor(s5, 1); s5 += __shfl_xor(s5, 2); s5 += __shfl_xor(s5, 4);
    if (q == 0) {
        s0 += b2[a * 6 + 0];
        s2 += b2[a * 6 + 2];
        s3 += b2[a * 6 + 3];
        s4 += b2[a * 6 + 4];
        s5 += b2[a * 6 + 5];
        float conf = 1.f / (1.f + expf(-s0));
        float x = (float)(p & 31), yy = (float)(p >> 5);
        float cx = x + 0.5f, cy = yy + 0.5f;
        float aw = anchors[a * 2 + 0], ah = anchors[a * 2 + 1];
        float pcx = cx + s2 * aw, pcy = cy + s3 * ah;
        float pw = aw * expf(s4), ph = ah * expf(s5);
        int idx = p * 9 + a;   // (y,x,a) flat order
        boxes[idx * 4 + 0] = pcx - pw / 2.f;
        boxes[idx * 4 + 1] = pcy - ph / 2.f;
        boxes[idx * 4 + 2] = pcx + pw / 2.f;
        boxes[idx * 4 + 3] = pcy + ph / 2.f;
        conf_arr[idx] = conf;
        bool valid = conf > 0.5f;
        float score = valid ? conf : -1.0f;
        unsigned int sb = __float_as_uint(score);
        sb = (sb & 0x80000000u) ? ~sb : (sb | 0x80000000u);
        keys[idx] = ((u64)sb << 32) | (unsigned int)(~idx);
        if (valid) atomicAdd(Vcnt, 1);
    }
}

// ============ rank (stable argsort) via pairwise count, j-split ============
__global__ __launch_bounds__(256) void rank_partial(const u64* __restrict__ keys,
                                                    int* __restrict__ rpart) {
    __shared__ u64 sk[256];
    int i = blockIdx.x * 256 + threadIdx.x;
    sk[threadIdx.x] = keys[blockIdx.y * 256 + threadIdx.x];
    __syncthreads();
    u64 ki = keys[i];
    int c = 0;
#pragma unroll 8
    for (int j = 0; j < 256; ++j) c += (sk[j] > ki) ? 1 : 0;
    rpart[blockIdx.y * NBOX + i] = c;
}

// ============ rank reduce + gather fused: order + sorted boxes + areas ============
__global__ __launch_bounds__(256) void rank_reduce_gather(const int* __restrict__ rpart,
                                                          const float* __restrict__ boxes,
                                                          int* __restrict__ order,
                                                          float* __restrict__ sbox,
                                                          float* __restrict__ sarea) {
    int i = blockIdx.x * 256 + threadIdx.x;
    int r = 0;
    for (int b = 0; b < 36; ++b) r += rpart[b * NBOX + i];
    order[r] = i;
    float x1 = boxes[i * 4 + 0], y1 = boxes[i * 4 + 1];
    float x2 = boxes[i * 4 + 2], y2 = boxes[i * 4 + 3];
    sbox[r * 4 + 0] = x1; sbox[r * 4 + 1] = y1;
    sbox[r * 4 + 2] = x2; sbox[r * 4 + 3] = y2;
    sarea[r] = fmaxf(x2 - x1, 0.f) * fmaxf(y2 - y1, 0.f);
}

// ============ sparse overlap edge list: (i,j), i<j<V, IoU>0.7 ============
__global__ __launch_bounds__(256) void nms_edges(const float* __restrict__ sbox,
                                                 const float* __restrict__ sarea,
                                                 const int* __restrict__ Vp,
                                                 unsigned* __restrict__ edges,
                                                 int* __restrict__ Ecnt) {
    int V = *Vp;
    int lane = threadIdx.x & 63;
    for (int i = blockIdx.x; i < V; i += 512) {
        float x1i = sbox[i * 4 + 0], y1i = sbox[i * 4 + 1];
        float x2i = sbox[i * 4 + 2], y2i = sbox[i * 4 + 3];
        float ai = sarea[i];
        for (int j = i + 1 + threadIdx.x; ; j += 256) {
            bool active = (j < V);
            if (__ballot(active) == 0ull) break;
            bool hit = false;
            if (active) {
                float x1j = sbox[j * 4 + 0], y1j = sbox[j * 4 + 1];
                float x2j = sbox[j * 4 + 2], y2j = sbox[j * 4 + 3];
                float iw = fmaxf(fminf(x2i, x2j) - fmaxf(x1i, x1j), 0.f);
                float ih = fmaxf(fminf(y2i, y2j) - fmaxf(y1i, y1j), 0.f);
                float inter = iw * ih;
                float iou = inter / (ai + sarea[j] - inter + 1e-8f);
                hit = iou > 0.7f;
            }
            u64 bal = __ballot(hit);
            if (bal) {
                int cnt = __popcll(bal);
                unsigned base = 0;
                if (lane == 0) base = (unsigned)atomicAdd(Ecnt, cnt);
                base = (unsigned)__shfl((int)base, 0, 64);
                if (hit) {
                    int pos = (int)base + __popcll(bal & ((1ull << lane) - 1ull));
                    if (pos < ECAP) edges[pos] = ((unsigned)j << 16) | (unsigned)i;
                }
            }
        }
    }
}

// ============ resolve (Jacobi fixpoint) + finalize, fused ============
// sup[j] = OR_{edges (i,j)} !sup[i] is well-founded (j depends only on i<j)
// -> unique fixpoint = reference greedy result. Iterate until stable, then
// the same block writes all 9216x5 outputs (R6-validated fusion).
__global__ __launch_bounds__(256) void nms_resolve_finalize(
        const unsigned* __restrict__ edges,
        const int* __restrict__ Ep,
        const int* __restrict__ Vp,
        const int* __restrict__ order,
        const float* __restrict__ boxes,
        const float* __restrict__ conf_arr,
        float* __restrict__ out) {
    __shared__ unsigned se[ECAP];
    __shared__ u64 sup[2][144];
    __shared__ int chg;
    const int tid = threadIdx.x;
    int E = *Ep; if (E > ECAP) E = ECAP;
    const int V = *Vp;
    for (int e = tid; e < E; e += 256) se[e] = edges[e];
    for (int w = tid; w < 144; w += 256) sup[0][w] = 0;
    __syncthreads();
    int p = 0;
    for (int it = 0; it < E + 2; ++it) {
        for (int w = tid; w < 144; w += 256) sup[1 - p][w] = 0;
        if (tid == 0) chg = 0;
        __syncthreads();
        for (int e = tid; e < E; e += 256) {
            unsigned k = se[e];
            int i = (int)(k & 0xffffu), j = (int)(k >> 16);
            if (!((sup[p][i >> 6] >> (i & 63)) & 1ull))
                atomicOr(&sup[1 - p][j >> 6], 1ull << (j & 63));
        }
        __syncthreads();
        for (int w = tid; w < 144; w += 256)
            if (sup[1 - p][w] != sup[p][w]) chg = 1;   // benign race: all write 1
        __syncthreads();
        int done = !chg;      // uniform read
        __syncthreads();      // all reads complete before next iter's chg reset
        p ^= 1;
        if (done) break;
    }
    // finalize: write all 9216 x 5 outputs from this block
    for (int q = tid; q < NBOX; q += 256) {
        int o = order[q];
        bool keep = (q < V) && !((sup[p][q >> 6] >> (q & 63)) & 1ull);
        float k = keep ? 1.f : 0.f;
        out[o * 5 + 0] = boxes[o * 4 + 0] * k;
        out[o * 5 + 1] = boxes[o * 4 + 1] * k;
        out[o * 5 + 2] = boxes[o * 4 + 2] * k;
        out[o * 5 + 3] = boxes[o * 4 + 3] * k;
        out[o * 5 + 4] = conf_arr[o] * k;
    }
}

extern "C" void kernel_launch(void* const* d_in, const int* in_sizes, int n_in,
                              void* d_out, int out_size, void* d_ws, size_t ws_size,
                              hipStream_t stream) {
    const float* feat    = (const float*)d_in[0];
    const float* anchors = (const float*)d_in[1];
    const float* w1      = (const float*)d_in[2];
    const float* b1      = (const float*)d_in[3];
    const float* w2      = (const float*)d_in[4];
    const float* b2      = (const float*)d_in[5];
    float* out = (float*)d_out;

    char* ws = (char*)d_ws;
    float* partial = (float*)(ws + O_PART);    // 16 x 1 MiB
    float* h       = (float*)(ws + O_H);       // aliases partial slot 0
    float* boxes   = (float*)(ws + O_BOXES);
    float* conf    = (float*)(ws + O_CONF);
    u64*   keys    = (u64*)(ws + O_KEYS);
    int* rpart     = (int*)(ws + O_RPART);
    int* order     = (int*)(ws + O_ORDER);
    float* sbox    = (float*)(ws + O_SBOX);
    float* sarea   = (float*)(ws + O_SAREA);
    int* Vcnt      = (int*)(ws + O_VCNT);
    int* Ecnt      = (int*)(ws + O_ECNT);
    unsigned* edges = (unsigned*)(ws + O_EDGES);

    conv1_kernel<<<dim3(16, 64), 256, 0, stream>>>(feat, w1, partial, Vcnt);
    conv1_reduce<<<1024, 256, 0, stream>>>(partial, b1);
    conv2_decode<<<288, 256, 0, stream>>>(h, w2, b2, anchors, boxes, conf, keys, Vcnt);
    rank_partial<<<dim3(36, 36), 256, 0, stream>>>(keys, rpart);
    rank_reduce_gather<<<36, 256, 0, stream>>>(rpart, boxes, order, sbox, sarea);
    nms_edges<<<512, 256, 0, stream>>>(sbox, sarea, Vcnt, edges, Ecnt);
    nms_resolve_finalize<<<1, 256, 0, stream>>>(edges, Ecnt, Vcnt, order,
                                                boxes, conf, out);
}

// Round 19
// 201.804 us; speedup vs baseline: 1.1790x; 1.1790x over previous
//
#include <hip/hip_runtime.h>
#include <math.h>

#define NPIX 1024
#define NBOX 9216
#define ECAP 6144        // edge capacity (measured E ~ 500)

typedef unsigned long long u64;

// ---------------- workspace layout (bytes), R5/R10 layout ----------------
#define O_PART     0u           // 16 x 1 MiB (16 x 262144 f32)
#define O_H        0u           // aliases partial slot 0
#define O_BOXES    1048576u     // 9216*4 f32
#define O_CONF     1196032u     // 9216 f32
#define O_KEYS     1232896u     // 9216 u64
#define O_ORDER    1306624u     // 9216 i32
#define O_SBOX     1343488u     // 9216*4 f32
#define O_SAREA    1490944u     // 9216 f32
#define O_EDGES    1527808u     // 6144 u32
#define O_KEEPW    1552384u     // 192 u64
#define O_RPART    1553920u     // 36*9216 i32 -> ends 2881024
#define O_VCNT     16777216u    // 1 i32 (Ecnt at +4)
#define O_ECNT     16777220u

// R17/R18 were consecutive infra failures ("container failed twice") on a
// byte-equivalent resubmit of R15's PASSING kernel (204.1us). R7->R8
// precedent: broker failures streak and clear on retry. R19 = third
// identical resubmit. Configuration is the session's accumulated optimum:
// R5 conv1 (6-probe neighborhood exhausted: pad/DMA/SGPR-pipeline/co 2-4-8
// all regressed) + R10 7-dispatch tail (all four fusion families measured
// worse) + R15 Jacobi resolve (the one clean tail win, -22us).

// ============ conv1: 3x3 SAME, 1280->256, fp32 (R5 form) ============
__global__ __launch_bounds__(256, 4) void conv1_kernel(const float* __restrict__ feat,
                                                       const float* __restrict__ w1,
                                                       float* __restrict__ partial,
                                                       int* __restrict__ VE) {
    const int kc  = blockIdx.x;          // 0..15
    const int cog = blockIdx.y;          // 0..63
    const int tid = threadIdx.x;
    const int x0 = (tid & 7) * 4;        // strip start col
    const int y  = tid >> 3;             // row 0..31
    const int ci0 = kc * 80;
    const int co0 = cog * 4;

    if (kc == 0 && cog == 0 && tid < 2) VE[tid] = 0;   // Vcnt/Ecnt zero (pre-conv2)

    __shared__ float sf[8 * 34 * 32];    // 34.8 KB (only LDS use)

    for (int e = tid; e < 8 * 2 * 32; e += 256) {
        int ci_l = e >> 6, r = (e >> 5) & 1, c = e & 31;
        sf[(ci_l * 34 + r * 33) * 32 + c] = 0.f;
    }

    float acc[4][4];
#pragma unroll
    for (int a = 0; a < 4; ++a)
#pragma unroll
        for (int b = 0; b < 4; ++b) acc[a][b] = 0.f;

    // block-uniform weight base; weight reads are s_load (SMEM pipe),
    // loaded just-before-use (R5 schedule - measured best; R8/R14 regressed).
    const float* wbase = w1 + (size_t)co0 * 11520 + (size_t)ci0 * 9;

    for (int chunk = 0; chunk < 10; ++chunk) {
        const int cbase = ci0 + chunk * 8;
        __syncthreads();
        {
            const float4* fg = (const float4*)(feat + (size_t)cbase * NPIX);
#pragma unroll
            for (int k = 0; k < 8; ++k) {
                int e = tid + k * 256;           // 0..2047
                int ci_l = e >> 8, rem = e & 255;
                int row = rem >> 3, f4c = rem & 7;
                float4 v = fg[ci_l * 256 + rem];
                *(float4*)&sf[(ci_l * 34 + row + 1) * 32 + f4c * 4] = v;
            }
        }
        __syncthreads();

#pragma unroll
        for (int cil = 0; cil < 8; ++cil) {
            float f[3][6];
            const float* base = &sf[(cil * 34 + y) * 32];
#pragma unroll
            for (int dy = 0; dy < 3; ++dy) {
                const float* rp = base + dy * 32;
                float4 mid = *(const float4*)(rp + x0);
                // halo via DPP (VALU pipe). 16-lane row boundary contamination
                // only reaches lanes whose halo is masked (x0==0 / x0==28).
                float lft = __int_as_float(__builtin_amdgcn_update_dpp(
                    0, __float_as_int(mid.w), 0x111 /*row_shr:1*/, 0xF, 0xF, true));
                float rgt = __int_as_float(__builtin_amdgcn_update_dpp(
                    0, __float_as_int(mid.x), 0x101 /*row_shl:1*/, 0xF, 0xF, true));
                f[dy][0] = (x0 == 0) ? 0.f : lft;
                f[dy][1] = mid.x; f[dy][2] = mid.y; f[dy][3] = mid.z; f[dy][4] = mid.w;
                f[dy][5] = (x0 == 28) ? 0.f : rgt;
            }
#pragma unroll
            for (int co = 0; co < 4; ++co) {
                const float* wrow = wbase + (size_t)co * 11520 +
                                    (size_t)(chunk * 8 + cil) * 9;
                float wv[9];
#pragma unroll
                for (int t = 0; t < 9; ++t) wv[t] = wrow[t];
#pragma unroll
                for (int dy = 0; dy < 3; ++dy)
#pragma unroll
                    for (int dx = 0; dx < 3; ++dx) {
                        float wgt = wv[dy * 3 + dx];
#pragma unroll
                        for (int px = 0; px < 4; ++px)
                            acc[co][px] = fmaf(f[dy][px + dx], wgt, acc[co][px]);
                    }
            }
        }
    }

    const int pix = y * 32 + x0;
#pragma unroll
    for (int co = 0; co < 4; ++co) {
        float4 v = {acc[co][0], acc[co][1], acc[co][2], acc[co][3]};
        *(float4*)&partial[((size_t)kc * 256 + co0 + co) * NPIX + pix] = v;
    }
}

// ============ reduce 16 partials + bias + leaky relu (in place: h = slot 0) ============
__global__ __launch_bounds__(256) void conv1_reduce(float* part_h,
                                                    const float* __restrict__ b1) {
    int i = blockIdx.x * 256 + threadIdx.x;
    float s = b1[i >> 10];
#pragma unroll
    for (int kc = 0; kc < 16; ++kc) s += part_h[(size_t)kc * 262144 + i];
    part_h[i] = s > 0.f ? s : 0.01f * s;   // per-thread RAW only
}

// ============ conv2 (1x1) + sigmoid + box decode + sort keys ============
__global__ __launch_bounds__(256) void conv2_decode(const float* __restrict__ h,
                                                    const float* __restrict__ w2,
                                                    const float* __restrict__ b2,
                                                    const float* __restrict__ anchors,
                                                    float* __restrict__ boxes,
                                                    float* __restrict__ conf_arr,
                                                    u64* __restrict__ keys,
                                                    int* __restrict__ Vcnt) {
    int gid = blockIdx.x * 256 + threadIdx.x;   // 0..73727
    int box = gid >> 3, q = gid & 7;            // 8 lanes per box
    int a = box >> 10, p = box & 1023;
    const float* hq  = h + (size_t)(q * 32) * NPIX + p;
    const float* wq  = w2 + (size_t)(a * 6) * 256 + q * 32;
    float s0 = 0.f, s2 = 0.f, s3 = 0.f, s4 = 0.f, s5 = 0.f;
#pragma unroll 4
    for (int ci = 0; ci < 32; ++ci) {
        float hv = hq[(size_t)ci * NPIX];
        s0 = fmaf(hv, wq[0 * 256 + ci], s0);
        s2 = fmaf(hv, wq[2 * 256 + ci], s2);
        s3 = fmaf(hv, wq[3 * 256 + ci], s3);
        s4 = fmaf(hv, wq[4 * 256 + ci], s4);
        s5 = fmaf(hv, wq[5 * 256 + ci], s5);
    }
    s0 += __shfl_xor(s0, 1); s0 += __shfl_xor(s0, 2); s0 += __shfl_xor(s0, 4);
    s2 += __shfl_xor(s2, 1); s2 += __shfl_xor(s2, 2); s2 += __shfl_xor(s2, 4);
    s3 += __shfl_xor(s3, 1); s3 += __shfl_xor(s3, 2); s3 += __shfl_xor(s3, 4);
    s4 += __shfl_xor(s4, 1); s4 += __shfl_xor(s4, 2); s4 += __shfl_xor(s4, 4);
    s5 += __shfl_xor(s5, 1); s5 += __shfl_xor(s5, 2); s5 += __shfl_xor(s5, 4);
    if (q == 0) {
        s0 += b2[a * 6 + 0];
        s2 += b2[a * 6 + 2];
        s3 += b2[a * 6 + 3];
        s4 += b2[a * 6 + 4];
        s5 += b2[a * 6 + 5];
        float conf = 1.f / (1.f + expf(-s0));
        float x = (float)(p & 31), yy = (float)(p >> 5);
        float cx = x + 0.5f, cy = yy + 0.5f;
        float aw = anchors[a * 2 + 0], ah = anchors[a * 2 + 1];
        float pcx = cx + s2 * aw, pcy = cy + s3 * ah;
        float pw = aw * expf(s4), ph = ah * expf(s5);
        int idx = p * 9 + a;   // (y,x,a) flat order
        boxes[idx * 4 + 0] = pcx - pw / 2.f;
        boxes[idx * 4 + 1] = pcy - ph / 2.f;
        boxes[idx * 4 + 2] = pcx + pw / 2.f;
        boxes[idx * 4 + 3] = pcy + ph / 2.f;
        conf_arr[idx] = conf;
        bool valid = conf > 0.5f;
        float score = valid ? conf : -1.0f;
        unsigned int sb = __float_as_uint(score);
        sb = (sb & 0x80000000u) ? ~sb : (sb | 0x80000000u);
        keys[idx] = ((u64)sb << 32) | (unsigned int)(~idx);
        if (valid) atomicAdd(Vcnt, 1);
    }
}

// ============ rank (stable argsort) via pairwise count, j-split ============
__global__ __launch_bounds__(256) void rank_partial(const u64* __restrict__ keys,
                                                    int* __restrict__ rpart) {
    __shared__ u64 sk[256];
    int i = blockIdx.x * 256 + threadIdx.x;
    sk[threadIdx.x] = keys[blockIdx.y * 256 + threadIdx.x];
    __syncthreads();
    u64 ki = keys[i];
    int c = 0;
#pragma unroll 8
    for (int j = 0; j < 256; ++j) c += (sk[j] > ki) ? 1 : 0;
    rpart[blockIdx.y * NBOX + i] = c;
}

// ============ rank reduce + gather fused: order + sorted boxes + areas ============
__global__ __launch_bounds__(256) void rank_reduce_gather(const int* __restrict__ rpart,
                                                          const float* __restrict__ boxes,
                                                          int* __restrict__ order,
                                                          float* __restrict__ sbox,
                                                          float* __restrict__ sarea) {
    int i = blockIdx.x * 256 + threadIdx.x;
    int r = 0;
    for (int b = 0; b < 36; ++b) r += rpart[b * NBOX + i];
    order[r] = i;
    float x1 = boxes[i * 4 + 0], y1 = boxes[i * 4 + 1];
    float x2 = boxes[i * 4 + 2], y2 = boxes[i * 4 + 3];
    sbox[r * 4 + 0] = x1; sbox[r * 4 + 1] = y1;
    sbox[r * 4 + 2] = x2; sbox[r * 4 + 3] = y2;
    sarea[r] = fmaxf(x2 - x1, 0.f) * fmaxf(y2 - y1, 0.f);
}

// ============ sparse overlap edge list: (i,j), i<j<V, IoU>0.7 ============
__global__ __launch_bounds__(256) void nms_edges(const float* __restrict__ sbox,
                                                 const float* __restrict__ sarea,
                                                 const int* __restrict__ Vp,
                                                 unsigned* __restrict__ edges,
                                                 int* __restrict__ Ecnt) {
    int V = *Vp;
    int lane = threadIdx.x & 63;
    for (int i = blockIdx.x; i < V; i += 2048) {
        float x1i = sbox[i * 4 + 0], y1i = sbox[i * 4 + 1];
        float x2i = sbox[i * 4 + 2], y2i = sbox[i * 4 + 3];
        float ai = sarea[i];
        for (int j = i + 1 + threadIdx.x; ; j += 256) {
            bool active = (j < V);
            if (__ballot(active) == 0ull) break;
            bool hit = false;
            if (active) {
                float x1j = sbox[j * 4 + 0], y1j = sbox[j * 4 + 1];
                float x2j = sbox[j * 4 + 2], y2j = sbox[j * 4 + 3];
                float iw = fmaxf(fminf(x2i, x2j) - fmaxf(x1i, x1j), 0.f);
                float ih = fmaxf(fminf(y2i, y2j) - fmaxf(y1i, y1j), 0.f);
                float inter = iw * ih;
                float iou = inter / (ai + sarea[j] - inter + 1e-8f);
                hit = iou > 0.7f;
            }
            u64 bal = __ballot(hit);
            if (bal) {
                int cnt = __popcll(bal);
                unsigned base = 0;
                if (lane == 0) base = (unsigned)atomicAdd(Ecnt, cnt);
                base = (unsigned)__shfl((int)base, 0, 64);
                if (hit) {
                    int pos = (int)base + __popcll(bal & ((1ull << lane) - 1ull));
                    if (pos < ECAP) edges[pos] = ((unsigned)j << 16) | (unsigned)i;
                }
            }
        }
    }
}

// ============ resolve: parallel Jacobi fixpoint ============
// sup[j] = OR_{edges (i,j)} !sup[i] is well-founded (j depends only on i<j)
// -> unique fixpoint = the reference's greedy result. Iterate all 256 threads
// until a full pass changes nothing (stable => fixpoint => exact). Edge order
// is irrelevant, so the O(E^2) sort is gone; so is the serial tid0 chain.
__global__ __launch_bounds__(256) void nms_resolve(const unsigned* __restrict__ edges,
                                                   const int* __restrict__ Ep,
                                                   const int* __restrict__ Vp,
                                                   u64* __restrict__ keepw) {
    __shared__ unsigned se[ECAP];
    __shared__ u64 sup[2][144];
    __shared__ int chg;
    const int tid = threadIdx.x;
    int E = *Ep; if (E > ECAP) E = ECAP;
    const int V = *Vp;
    for (int e = tid; e < E; e += 256) se[e] = edges[e];
    for (int w = tid; w < 144; w += 256) sup[0][w] = 0;
    __syncthreads();
    int p = 0;
    for (int it = 0; it < E + 2; ++it) {
        for (int w = tid; w < 144; w += 256) sup[1 - p][w] = 0;
        if (tid == 0) chg = 0;
        __syncthreads();
        for (int e = tid; e < E; e += 256) {
            unsigned k = se[e];
            int i = (int)(k & 0xffffu), j = (int)(k >> 16);
            if (!((sup[p][i >> 6] >> (i & 63)) & 1ull))
                atomicOr(&sup[1 - p][j >> 6], 1ull << (j & 63));
        }
        __syncthreads();
        for (int w = tid; w < 144; w += 256)
            if (sup[1 - p][w] != sup[p][w]) chg = 1;   // benign race: all write 1
        __syncthreads();
        int done = !chg;      // uniform read
        __syncthreads();      // all reads complete before next iter's chg reset
        p ^= 1;
        if (done) break;
    }
    for (int w = tid; w < 144; w += 256) {
        int base = w * 64;
        u64 vm;
        if (base + 64 <= V) vm = ~0ull;
        else if (base >= V) vm = 0ull;
        else vm = (1ull << (V - base)) - 1ull;
        keepw[w] = ~sup[p][w] & vm;
    }
}

// ============ final output write (all 9216 x 5) ============
__global__ __launch_bounds__(256) void finalize(const int* __restrict__ order,
                                                const int* __restrict__ Vp,
                                                const u64* __restrict__ keepw,
                                                const float* __restrict__ boxes,
                                                const float* __restrict__ conf_arr,
                                                float* __restrict__ out) {
    int p = blockIdx.x * 256 + threadIdx.x;   // sorted position
    int V = *Vp;
    int o = order[p];
    bool keep = false;
    if (p < V) keep = (keepw[p >> 6] >> (p & 63)) & 1ull;
    float k = keep ? 1.f : 0.f;
    out[o * 5 + 0] = boxes[o * 4 + 0] * k;
    out[o * 5 + 1] = boxes[o * 4 + 1] * k;
    out[o * 5 + 2] = boxes[o * 4 + 2] * k;
    out[o * 5 + 3] = boxes[o * 4 + 3] * k;
    out[o * 5 + 4] = conf_arr[o] * k;
}

extern "C" void kernel_launch(void* const* d_in, const int* in_sizes, int n_in,
                              void* d_out, int out_size, void* d_ws, size_t ws_size,
                              hipStream_t stream) {
    const float* feat    = (const float*)d_in[0];
    const float* anchors = (const float*)d_in[1];
    const float* w1      = (const float*)d_in[2];
    const float* b1      = (const float*)d_in[3];
    const float* w2      = (const float*)d_in[4];
    const float* b2      = (const float*)d_in[5];
    float* out = (float*)d_out;

    char* ws = (char*)d_ws;
    float* partial = (float*)(ws + O_PART);    // 16 x 1 MiB
    float* h       = (float*)(ws + O_H);       // aliases partial slot 0
    float* boxes   = (float*)(ws + O_BOXES);
    float* conf    = (float*)(ws + O_CONF);
    u64*   keys    = (u64*)(ws + O_KEYS);
    int* rpart     = (int*)(ws + O_RPART);
    int* order     = (int*)(ws + O_ORDER);
    float* sbox    = (float*)(ws + O_SBOX);
    float* sarea   = (float*)(ws + O_SAREA);
    int* Vcnt      = (int*)(ws + O_VCNT);
    int* Ecnt      = (int*)(ws + O_ECNT);
    u64* keepw     = (u64*)(ws + O_KEEPW);
    unsigned* edges = (unsigned*)(ws + O_EDGES);

    conv1_kernel<<<dim3(16, 64), 256, 0, stream>>>(feat, w1, partial, Vcnt);
    conv1_reduce<<<1024, 256, 0, stream>>>(partial, b1);
    conv2_decode<<<288, 256, 0, stream>>>(h, w2, b2, anchors, boxes, conf, keys, Vcnt);
    rank_partial<<<dim3(36, 36), 256, 0, stream>>>(keys, rpart);
    rank_reduce_gather<<<36, 256, 0, stream>>>(rpart, boxes, order, sbox, sarea);
    nms_edges<<<2048, 256, 0, stream>>>(sbox, sarea, Vcnt, edges, Ecnt);
    nms_resolve<<<1, 256, 0, stream>>>(edges, Ecnt, Vcnt, keepw);
    finalize<<<36, 256, 0, stream>>>(order, Vcnt, keepw, boxes, conf, out);
}